// Round 2
// baseline (800.960 us; speedup 1.0000x reference)
//
#include <hip/hip_runtime.h>

#define D 256
#define H 256
#define O 24
#define R 32   // rows per block

// Fused 3-layer MLP + top-6-of-22 mask.
// Block: 256 threads. L1/L2: thread tile = 4 rows x 8 cols (cols c0..c0+3 and
// c0+128..c0+131 so W loads stay lane-contiguous). Activations read from LDS
// as ds_read_b128 (1 per row per 4-k chunk) -> LDS pipe no longer the bottleneck.
// LDS: bufA (x tile, later h2) + bufB (h1, later logits+selmask) = 64 KB.
__global__ __launch_bounds__(256, 2) void fused_mlp_topk(
    const float* __restrict__ x,  const float* __restrict__ W1, const float* __restrict__ b1,
    const float* __restrict__ W2, const float* __restrict__ b2,
    const float* __restrict__ W3, const float* __restrict__ b3,
    float* __restrict__ out)
{
    __shared__ float bufA[R][D];   // x tile, then h2
    __shared__ float bufB[R][H];   // h1; later overlaid with logits + selmask

    float (*logits)[O] = (float (*)[O])(&bufB[0][0]);
    unsigned int* selmask = (unsigned int*)(&bufB[0][0] + R * O);

    const int t = threadIdx.x;
    const long row0 = (long)blockIdx.x * R;

    // ---- stage x tile: 32 rows x 256 cols, coalesced float4 ----
    {
        const int tt = t & 63;
        const int rr = t >> 6;
        #pragma unroll
        for (int r = rr; r < R; r += 4)
            *(float4*)(&bufA[r][4 * tt]) = *(const float4*)(x + (row0 + r) * D + 4 * tt);
    }
    __syncthreads();

    const int c0 = (t & 31) * 4;   // col quads: c0 and c0+128
    const int r0 = (t >> 5) * 4;   // rows r0..r0+3

    float acc[4][8];

    // ---- Layer 1: bufB = relu(bufA @ W1 + b1) ----
    {
        float4 ba = *(const float4*)(b1 + c0);
        float4 bb = *(const float4*)(b1 + c0 + 128);
        #pragma unroll
        for (int r = 0; r < 4; ++r) {
            acc[r][0]=ba.x; acc[r][1]=ba.y; acc[r][2]=ba.z; acc[r][3]=ba.w;
            acc[r][4]=bb.x; acc[r][5]=bb.y; acc[r][6]=bb.z; acc[r][7]=bb.w;
        }
        for (int kc = 0; kc < D; kc += 4) {
            float4 xr[4];
            #pragma unroll
            for (int r = 0; r < 4; ++r)
                xr[r] = *(const float4*)(&bufA[r0 + r][kc]);   // wave-broadcast b128
            #pragma unroll
            for (int i = 0; i < 4; ++i) {
                float4 wa = *(const float4*)(W1 + (size_t)(kc + i) * H + c0);
                float4 wb = *(const float4*)(W1 + (size_t)(kc + i) * H + c0 + 128);
                #pragma unroll
                for (int r = 0; r < 4; ++r) {
                    const float xv = (&xr[r].x)[i];
                    acc[r][0] = fmaf(xv, wa.x, acc[r][0]);
                    acc[r][1] = fmaf(xv, wa.y, acc[r][1]);
                    acc[r][2] = fmaf(xv, wa.z, acc[r][2]);
                    acc[r][3] = fmaf(xv, wa.w, acc[r][3]);
                    acc[r][4] = fmaf(xv, wb.x, acc[r][4]);
                    acc[r][5] = fmaf(xv, wb.y, acc[r][5]);
                    acc[r][6] = fmaf(xv, wb.z, acc[r][6]);
                    acc[r][7] = fmaf(xv, wb.w, acc[r][7]);
                }
            }
        }
        #pragma unroll
        for (int r = 0; r < 4; ++r) {
            float4 va = make_float4(fmaxf(acc[r][0],0.f), fmaxf(acc[r][1],0.f),
                                    fmaxf(acc[r][2],0.f), fmaxf(acc[r][3],0.f));
            float4 vb = make_float4(fmaxf(acc[r][4],0.f), fmaxf(acc[r][5],0.f),
                                    fmaxf(acc[r][6],0.f), fmaxf(acc[r][7],0.f));
            *(float4*)(&bufB[r0 + r][c0])       = va;
            *(float4*)(&bufB[r0 + r][c0 + 128]) = vb;
        }
    }
    __syncthreads();

    // ---- Layer 2: bufA = relu(bufB @ W2 + b2) ----
    {
        float4 ba = *(const float4*)(b2 + c0);
        float4 bb = *(const float4*)(b2 + c0 + 128);
        #pragma unroll
        for (int r = 0; r < 4; ++r) {
            acc[r][0]=ba.x; acc[r][1]=ba.y; acc[r][2]=ba.z; acc[r][3]=ba.w;
            acc[r][4]=bb.x; acc[r][5]=bb.y; acc[r][6]=bb.z; acc[r][7]=bb.w;
        }
        for (int kc = 0; kc < H; kc += 4) {
            float4 hr[4];
            #pragma unroll
            for (int r = 0; r < 4; ++r)
                hr[r] = *(const float4*)(&bufB[r0 + r][kc]);
            #pragma unroll
            for (int i = 0; i < 4; ++i) {
                float4 wa = *(const float4*)(W2 + (size_t)(kc + i) * H + c0);
                float4 wb = *(const float4*)(W2 + (size_t)(kc + i) * H + c0 + 128);
                #pragma unroll
                for (int r = 0; r < 4; ++r) {
                    const float hv = (&hr[r].x)[i];
                    acc[r][0] = fmaf(hv, wa.x, acc[r][0]);
                    acc[r][1] = fmaf(hv, wa.y, acc[r][1]);
                    acc[r][2] = fmaf(hv, wa.z, acc[r][2]);
                    acc[r][3] = fmaf(hv, wa.w, acc[r][3]);
                    acc[r][4] = fmaf(hv, wb.x, acc[r][4]);
                    acc[r][5] = fmaf(hv, wb.y, acc[r][5]);
                    acc[r][6] = fmaf(hv, wb.z, acc[r][6]);
                    acc[r][7] = fmaf(hv, wb.w, acc[r][7]);
                }
            }
        }
        #pragma unroll
        for (int r = 0; r < 4; ++r) {
            float4 va = make_float4(fmaxf(acc[r][0],0.f), fmaxf(acc[r][1],0.f),
                                    fmaxf(acc[r][2],0.f), fmaxf(acc[r][3],0.f));
            float4 vb = make_float4(fmaxf(acc[r][4],0.f), fmaxf(acc[r][5],0.f),
                                    fmaxf(acc[r][6],0.f), fmaxf(acc[r][7],0.f));
            *(float4*)(&bufA[r0 + r][c0])       = va;
            *(float4*)(&bufA[r0 + r][c0 + 128]) = vb;
        }
    }
    __syncthreads();

    // ---- Layer 3: logits = h2 @ W3 + b3 (768 dots of length 256) ----
    // thread t: row = t>>3, cols jb..jb+2. h2 read once per 4-k chunk (b128),
    // W3 via scalar global loads (24 KB, L1-hot, vmem pipe not LDS pipe).
    {
        const int r  = t >> 3;
        const int jb = (t & 7) * 3;
        float a0 = b3[jb], a1 = b3[jb + 1], a2 = b3[jb + 2];
        for (int kc = 0; kc < H; kc += 4) {
            float4 h = *(const float4*)(&bufA[r][kc]);
            #pragma unroll
            for (int i = 0; i < 4; ++i) {
                const float hv = (&h.x)[i];
                const float* wrow = W3 + (size_t)(kc + i) * O + jb;
                a0 = fmaf(hv, wrow[0], a0);
                a1 = fmaf(hv, wrow[1], a1);
                a2 = fmaf(hv, wrow[2], a2);
            }
        }
        __syncthreads();                 // bufB (h1) dead -> reuse as logits
        logits[r][jb]     = a0;
        logits[r][jb + 1] = a1;
        logits[r][jb + 2] = a2;
    }
    __syncthreads();

    // ---- top-6 of the 22 selected columns (cols != 0,12), one thread per row ----
    if (t < R) {
        float v[22];
        #pragma unroll
        for (int i = 0; i < 22; ++i) {
            const int j = (i < 11) ? (i + 1) : (i + 2);
            v[i] = logits[t][j];
        }
        unsigned taken = 0u;
        unsigned cm = 1u | (1u << 12);
        for (int kk = 0; kk < 6; ++kk) {
            float best = -3.4e38f; int bi = 0;
            #pragma unroll
            for (int i = 0; i < 22; ++i) {
                if (!((taken >> i) & 1u) && v[i] > best) { best = v[i]; bi = i; }
            }
            taken |= 1u << bi;
            cm |= 1u << ((bi < 11) ? (bi + 1) : (bi + 2));
        }
        selmask[t] = cm;
    }
    __syncthreads();

    // ---- write mask (coalesced) ----
    for (int id = t; id < R * O; id += 256) {
        const int r = id / O;
        const int j = id - r * O;
        out[row0 * O + id] = ((selmask[r] >> j) & 1u) ? 1.0f : 0.0f;
    }
}

extern "C" void kernel_launch(void* const* d_in, const int* in_sizes, int n_in,
                              void* d_out, int out_size, void* d_ws, size_t ws_size,
                              hipStream_t stream) {
    const float* x  = (const float*)d_in[0];
    const float* W1 = (const float*)d_in[1];
    const float* b1 = (const float*)d_in[2];
    const float* W2 = (const float*)d_in[3];
    const float* b2 = (const float*)d_in[4];
    const float* W3 = (const float*)d_in[5];
    const float* b3 = (const float*)d_in[6];
    float* out = (float*)d_out;

    const int B = in_sizes[0] / D;   // 131072
    const int nblk = B / R;          // 4096
    hipLaunchKernelGGL(fused_mlp_topk, dim3(nblk), dim3(256), 0, stream,
                       x, W1, b1, W2, b2, W3, b3, out);
}

// Round 3
// 773.768 us; speedup vs baseline: 1.0351x; 1.0351x over previous
//
#include <hip/hip_runtime.h>

#define D 256
#define H 256
#define O 24
#define R 64    // rows per block
#define T 512   // threads per block (8 waves)

// Fused 3-layer MLP + top-6-of-22 mask.
// Single 64KB LDS buffer reused in place: x -> h1 -> h2 -> logits.
// Wave = 1 row-group (8 rows) x 64 col-groups (4 cols each) = perfect W
// coalescing (one dwordx4 per k, 1KB distinct per instr, shared stream
// across all 16 resident waves -> L1 hits). Activations via broadcast
// ds_read_b128. 2 blocks/CU = 4 waves/SIMD for latency hiding.

__device__ __forceinline__ void mlp_layer(const float (*in)[D],
                                          const float* __restrict__ W,
                                          const float* __restrict__ b,
                                          int c0, int r0, float acc[8][4])
{
    float4 bias = *(const float4*)(b + c0);
    #pragma unroll
    for (int r = 0; r < 8; ++r) {
        acc[r][0] = bias.x; acc[r][1] = bias.y; acc[r][2] = bias.z; acc[r][3] = bias.w;
    }
    for (int kc = 0; kc < D; kc += 4) {
        float4 xr[8];
        #pragma unroll
        for (int r = 0; r < 8; ++r)
            xr[r] = *(const float4*)(&in[r0 + r][kc]);   // wave-broadcast b128
        #pragma unroll
        for (int i = 0; i < 4; ++i) {
            float4 w = *(const float4*)(W + (size_t)(kc + i) * H + c0);
            #pragma unroll
            for (int r = 0; r < 8; ++r) {
                const float xv = (&xr[r].x)[i];
                acc[r][0] = fmaf(xv, w.x, acc[r][0]);
                acc[r][1] = fmaf(xv, w.y, acc[r][1]);
                acc[r][2] = fmaf(xv, w.z, acc[r][2]);
                acc[r][3] = fmaf(xv, w.w, acc[r][3]);
            }
        }
    }
}

__global__ __launch_bounds__(T, 4) void fused_mlp_topk(
    const float* __restrict__ x,  const float* __restrict__ W1, const float* __restrict__ b1,
    const float* __restrict__ W2, const float* __restrict__ b2,
    const float* __restrict__ W3, const float* __restrict__ b3,
    float* __restrict__ out)
{
    __shared__ float buf[R][D];   // 64 KB, reused in place

    float (*logits)[O] = (float (*)[O])(&buf[0][0]);
    unsigned int* selmask = (unsigned int*)(&buf[0][0] + R * O);

    const int t = threadIdx.x;
    const long row0 = (long)blockIdx.x * R;

    // ---- stage x tile: 64 rows x 256 cols, coalesced float4 ----
    {
        const int tt = t & 63;
        const int rr = t >> 6;            // 0..7
        #pragma unroll
        for (int i = 0; i < 8; ++i) {
            const int r = rr + 8 * i;
            *(float4*)(&buf[r][4 * tt]) = *(const float4*)(x + (row0 + r) * D + 4 * tt);
        }
    }
    __syncthreads();

    const int c0 = (t & 63) * 4;      // cols c0..c0+3 (wave covers all 256)
    const int r0 = (t >> 6) * 8;      // rows r0..r0+7 (one row-group per wave)

    float acc[8][4];

    // ---- Layer 1: h1 = relu(x @ W1 + b1), written back in place ----
    mlp_layer(buf, W1, b1, c0, r0, acc);
    __syncthreads();                  // all reads of x done
    #pragma unroll
    for (int r = 0; r < 8; ++r) {
        float4 v = make_float4(fmaxf(acc[r][0],0.f), fmaxf(acc[r][1],0.f),
                               fmaxf(acc[r][2],0.f), fmaxf(acc[r][3],0.f));
        *(float4*)(&buf[r0 + r][c0]) = v;
    }
    __syncthreads();

    // ---- Layer 2: h2 = relu(h1 @ W2 + b2), in place ----
    mlp_layer(buf, W2, b2, c0, r0, acc);
    __syncthreads();
    #pragma unroll
    for (int r = 0; r < 8; ++r) {
        float4 v = make_float4(fmaxf(acc[r][0],0.f), fmaxf(acc[r][1],0.f),
                               fmaxf(acc[r][2],0.f), fmaxf(acc[r][3],0.f));
        *(float4*)(&buf[r0 + r][c0]) = v;
    }
    __syncthreads();

    // ---- Layer 3: logits = h2 @ W3 + b3 ----
    // thread t: row = t>>3 (0..63), cols jb..jb+2. h2 via broadcast-ish b128;
    // W3 (24 KB) is L1-hot, addresses span 1-2 cache lines per instr.
    {
        const int r  = t >> 3;
        const int jb = (t & 7) * 3;
        float a0 = b3[jb], a1 = b3[jb + 1], a2 = b3[jb + 2];
        for (int kc = 0; kc < H; kc += 4) {
            float4 h = *(const float4*)(&buf[r][kc]);
            #pragma unroll
            for (int i = 0; i < 4; ++i) {
                const float hv = (&h.x)[i];
                const float* wrow = W3 + (size_t)(kc + i) * O + jb;
                a0 = fmaf(hv, wrow[0], a0);
                a1 = fmaf(hv, wrow[1], a1);
                a2 = fmaf(hv, wrow[2], a2);
            }
        }
        __syncthreads();              // all reads of h2 done -> overlay logits
        logits[r][jb]     = a0;
        logits[r][jb + 1] = a1;
        logits[r][jb + 2] = a2;
    }
    __syncthreads();

    // ---- top-6 of the 22 selected columns (cols != 0,12), one thread per row ----
    if (t < R) {
        float v[22];
        #pragma unroll
        for (int i = 0; i < 22; ++i) {
            const int j = (i < 11) ? (i + 1) : (i + 2);
            v[i] = logits[t][j];
        }
        unsigned taken = 0u;
        unsigned cm = 1u | (1u << 12);
        for (int kk = 0; kk < 6; ++kk) {
            float best = -3.4e38f; int bi = 0;
            #pragma unroll
            for (int i = 0; i < 22; ++i) {
                if (!((taken >> i) & 1u) && v[i] > best) { best = v[i]; bi = i; }
            }
            taken |= 1u << bi;
            cm |= 1u << ((bi < 11) ? (bi + 1) : (bi + 2));
        }
        selmask[t] = cm;
    }
    __syncthreads();

    // ---- write mask (coalesced) ----
    for (int id = t; id < R * O; id += T) {
        const int r = id / O;
        const int j = id - r * O;
        out[row0 * O + id] = ((selmask[r] >> j) & 1u) ? 1.0f : 0.0f;
    }
}

extern "C" void kernel_launch(void* const* d_in, const int* in_sizes, int n_in,
                              void* d_out, int out_size, void* d_ws, size_t ws_size,
                              hipStream_t stream) {
    const float* x  = (const float*)d_in[0];
    const float* W1 = (const float*)d_in[1];
    const float* b1 = (const float*)d_in[2];
    const float* W2 = (const float*)d_in[3];
    const float* b2 = (const float*)d_in[4];
    const float* W3 = (const float*)d_in[5];
    const float* b3 = (const float*)d_in[6];
    float* out = (float*)d_out;

    const int B = in_sizes[0] / D;   // 131072
    const int nblk = B / R;          // 2048
    hipLaunchKernelGGL(fused_mlp_topk, dim3(nblk), dim3(T), 0, stream,
                       x, W1, b1, W2, b2, W3, b3, out);
}

// Round 4
// 448.062 us; speedup vs baseline: 1.7876x; 1.7269x over previous
//
#include <hip/hip_runtime.h>

#define D 256
#define H 256
#define O 24
#define R 64          // rows per block
#define T 256         // threads per block (4 waves)
#define LDSW 260      // fp32 LDS row stride: 16B-aligned (260*4=1040), good bank spread
#define LGW 25        // logits LDS stride

typedef __attribute__((ext_vector_type(4))) float f32x4;
typedef __attribute__((ext_vector_type(8))) unsigned short us8;
typedef __attribute__((ext_vector_type(8))) __bf16 bf16x8;
typedef __attribute__((ext_vector_type(4))) unsigned int u32x4;

// d_ws layout (ushort units):
//   wf1[3][8][16][64][8] @ 0        (196608 ush = 384 KB)
//   wf2[3][8][16][64][8] @ 196608   (384 KB)
//   wf3[3][8][ 2][64][8] @ 393216   ( 48 KB)
#define WF2_OFF 196608
#define WF3_OFF 393216

// Exact 3-piece bf16 split (RNE): v == h + m + l to ~2^-27 relative.
__device__ __forceinline__ void split3(float v, unsigned short& h, unsigned short& m,
                                       unsigned short& l) {
    unsigned u = __float_as_uint(v);
    unsigned hb = (u + 0x7fffu + ((u >> 16) & 1u)) >> 16;
    float r = v - __uint_as_float(hb << 16);
    unsigned ur = __float_as_uint(r);
    unsigned mb = (ur + 0x7fffu + ((ur >> 16) & 1u)) >> 16;
    float r2 = r - __uint_as_float(mb << 16);
    unsigned ul = __float_as_uint(r2);
    unsigned lb = (ul + 0x7fffu + ((ul >> 16) & 1u)) >> 16;
    h = (unsigned short)hb; m = (unsigned short)mb; l = (unsigned short)lb;
}

__device__ __forceinline__ f32x4 mfma16(us8 a, us8 b, f32x4 c) {
    return __builtin_amdgcn_mfma_f32_16x16x32_bf16(
        __builtin_bit_cast(bf16x8, a), __builtin_bit_cast(bf16x8, b), c, 0, 0, 0);
}

// ---- pre-split W1/W2/W3 into B-fragment-linear bf16 pieces ----
// B-frag for (kb,nb): lane holds B[k=kb*32+(lane>>4)*8+j][n=nb*16+(lane&15)], j=0..7.
// Stored lane-contiguous: ((p*8+kb)*NB+nb)*512 + lane*8 + j  (1KB per frag tile).
__global__ void split_w(const float* __restrict__ W1, const float* __restrict__ W2,
                        const float* __restrict__ W3, unsigned short* __restrict__ wf)
{
    const int bid = blockIdx.x;        // 0..271
    const int lane = threadIdx.x;      // 0..63
    const int q = lane >> 4, ln = lane & 15;
    const float* src; unsigned short* dst; int nbcnt, ld, ncols, kb, nb;
    if (bid < 256) {
        int mat = bid >> 7; kb = (bid >> 4) & 7; nb = bid & 15;
        src = mat ? W2 : W1; dst = wf + (mat ? WF2_OFF : 0);
        nbcnt = 16; ld = H; ncols = H;
    } else {
        int b = bid - 256; kb = b >> 1; nb = b & 1;
        src = W3; dst = wf + WF3_OFF; nbcnt = 2; ld = O; ncols = O;
    }
    const int n = nb * 16 + ln;
    const size_t pstride = (size_t)8 * nbcnt * 512;
    #pragma unroll
    for (int j = 0; j < 8; ++j) {
        const int k = kb * 32 + q * 8 + j;
        float v = (n < ncols) ? src[(size_t)k * ld + n] : 0.f;
        unsigned short h, m, l; split3(v, h, m, l);
        size_t base = ((size_t)kb * nbcnt + nb) * 512 + (size_t)lane * 8 + j;
        dst[base] = h; dst[base + pstride] = m; dst[base + 2 * pstride] = l;
    }
}

// One MFMA layer for a wave's 16-row strip. Reads fp32 activations from LDS
// (rows m0..m0+15, stride LDSW), splits to 3 bf16 A-frags per K-block, runs
// 6 passes vs pre-split B-frags. No cross-wave LDS hazard -> no barriers.
template <int NB>
__device__ __forceinline__ void mfma_layer(const float* __restrict__ hrow,
                                           const u32x4* __restrict__ wf,
                                           const float* __restrict__ bias, int ncols,
                                           int lane, f32x4* acc)
{
    const int ln = lane & 15, q = lane >> 4;
    #pragma unroll
    for (int nb = 0; nb < NB; ++nb) {
        const int c = nb * 16 + ln;
        const float bv = (c < ncols) ? bias[c] : 0.f;
        acc[nb] = (f32x4){bv, bv, bv, bv};
    }
    for (int kb = 0; kb < 8; ++kb) {
        const float* ap = hrow + (size_t)ln * LDSW + kb * 32 + q * 8;
        f32x4 x0 = *(const f32x4*)ap;          // ds_read_b128 (16B-aligned)
        f32x4 x1 = *(const f32x4*)(ap + 4);
        us8 ah, am, al;
        #pragma unroll
        for (int j = 0; j < 8; ++j) {
            const float v = (j < 4) ? x0[j] : x1[j - 4];
            unsigned short h, m, l; split3(v, h, m, l);
            ah[j] = h; am[j] = m; al[j] = l;
        }
        const u32x4* wp = wf + (size_t)kb * NB * 64 + lane;
        #pragma unroll
        for (int nb = 0; nb < NB; ++nb) {
            us8 bh = __builtin_bit_cast(us8, wp[(size_t)nb * 64]);
            us8 bm = __builtin_bit_cast(us8, wp[((size_t)8 * NB + nb) * 64]);
            us8 bl = __builtin_bit_cast(us8, wp[((size_t)16 * NB + nb) * 64]);
            acc[nb] = mfma16(ah, bh, acc[nb]);
            acc[nb] = mfma16(am, bh, acc[nb]);
            acc[nb] = mfma16(al, bh, acc[nb]);
            acc[nb] = mfma16(ah, bm, acc[nb]);
            acc[nb] = mfma16(am, bm, acc[nb]);
            acc[nb] = mfma16(ah, bl, acc[nb]);
        }
    }
}

__global__ __launch_bounds__(T, 2) void fused_mlp_topk(
    const float* __restrict__ x,
    const float* __restrict__ b1, const float* __restrict__ b2, const float* __restrict__ b3,
    const u32x4* __restrict__ wfrag, float* __restrict__ out)
{
    __shared__ float hbuf[R][LDSW];          // x -> h1 -> h2, in place (66560 B)
    __shared__ float logitsB[R][LGW];        // 6400 B
    __shared__ unsigned selmask[R];          // 256 B

    const int t = threadIdx.x;
    const int lane = t & 63, w = t >> 6;
    const int ln = lane & 15, q = lane >> 4;
    const long row0 = (long)blockIdx.x * R;

    // ---- stage x tile (coalesced f32x4; LDS b128 writes at structural min) ----
    #pragma unroll
    for (int ch = 0; ch < 16; ++ch) {
        const int idx = ch * T + t;
        const int r = idx >> 6, c4 = (idx & 63) * 4;
        *(f32x4*)&hbuf[r][c4] = *(const f32x4*)(x + (row0 + r) * D + c4);
    }
    __syncthreads();

    const int m0 = w * 16;
    f32x4 acc[16];

    // ---- Layer 1 ----
    mfma_layer<16>(&hbuf[m0][0], wfrag, b1, H, lane, acc);
    #pragma unroll
    for (int nb = 0; nb < 16; ++nb)
        #pragma unroll
        for (int rg = 0; rg < 4; ++rg)
            hbuf[m0 + q * 4 + rg][nb * 16 + ln] = fmaxf(acc[nb][rg], 0.f);

    // ---- Layer 2 ----
    mfma_layer<16>(&hbuf[m0][0], wfrag + WF2_OFF / 8, b2, H, lane, acc);
    #pragma unroll
    for (int nb = 0; nb < 16; ++nb)
        #pragma unroll
        for (int rg = 0; rg < 4; ++rg)
            hbuf[m0 + q * 4 + rg][nb * 16 + ln] = fmaxf(acc[nb][rg], 0.f);

    // ---- Layer 3 (2 col-tiles, cols 24..31 zero-padded in wf3) ----
    f32x4 acc3[2];
    mfma_layer<2>(&hbuf[m0][0], wfrag + WF3_OFF / 8, b3, O, lane, acc3);
    #pragma unroll
    for (int nb = 0; nb < 2; ++nb)
        #pragma unroll
        for (int rg = 0; rg < 4; ++rg) {
            const int c = nb * 16 + ln;
            if (c < O) logitsB[m0 + q * 4 + rg][c] = acc3[nb][rg];
        }
    __syncthreads();

    // ---- top-6 of the 22 selected columns (cols != 0,12), one thread per row ----
    if (t < R) {
        float v[22];
        #pragma unroll
        for (int i = 0; i < 22; ++i) {
            const int j = (i < 11) ? (i + 1) : (i + 2);
            v[i] = logitsB[t][j];
        }
        unsigned taken = 0u;
        unsigned cm = 1u | (1u << 12);
        for (int kk = 0; kk < 6; ++kk) {
            float best = -3.4e38f; int bi = 0;
            #pragma unroll
            for (int i = 0; i < 22; ++i) {
                if (!((taken >> i) & 1u) && v[i] > best) { best = v[i]; bi = i; }
            }
            taken |= 1u << bi;
            cm |= 1u << ((bi < 11) ? (bi + 1) : (bi + 2));
        }
        selmask[t] = cm;
    }
    __syncthreads();

    // ---- write mask (coalesced) ----
    #pragma unroll
    for (int i = 0; i < (R * O) / T; ++i) {
        const int idx = i * T + t;
        const int r = idx / O;
        const int j = idx - r * O;
        out[row0 * O + idx] = ((selmask[r] >> j) & 1u) ? 1.0f : 0.0f;
    }
}

extern "C" void kernel_launch(void* const* d_in, const int* in_sizes, int n_in,
                              void* d_out, int out_size, void* d_ws, size_t ws_size,
                              hipStream_t stream) {
    const float* x  = (const float*)d_in[0];
    const float* W1 = (const float*)d_in[1];
    const float* b1 = (const float*)d_in[2];
    const float* W2 = (const float*)d_in[3];
    const float* b2 = (const float*)d_in[4];
    const float* W3 = (const float*)d_in[5];
    const float* b3 = (const float*)d_in[6];
    float* out = (float*)d_out;

    unsigned short* wf = (unsigned short*)d_ws;
    hipLaunchKernelGGL(split_w, dim3(272), dim3(64), 0, stream, W1, W2, W3, wf);

    const int B = in_sizes[0] / D;   // 131072
    const int nblk = B / R;          // 2048
    hipLaunchKernelGGL(fused_mlp_topk, dim3(nblk), dim3(T), 0, stream,
                       x, b1, b2, b3, (const u32x4*)d_ws, out);
}